// Round 9
// baseline (219.258 us; speedup 1.0000x reference)
//
#include <hip/hip_runtime.h>

#define NUMH 2
#define BATCH 8
#define CCH 512
#define HWN 1024

typedef unsigned short u16;
typedef unsigned int u32;
typedef _Float16 f16;
typedef __attribute__((ext_vector_type(8))) _Float16 f16x8;
typedef __attribute__((ext_vector_type(8))) short bf16x8;
typedef __attribute__((ext_vector_type(4))) float f32x4;

__device__ __forceinline__ u16 f2h(float x) {
    union { f16 h; u16 u; } cv;
    cv.h = (f16)x;
    return cv.u;
}
__device__ __forceinline__ u16 f2bf(float x) {
    u32 u = __float_as_uint(x);
    return (u16)((u + 0x7fffu + ((u >> 16) & 1u)) >> 16);
}

__device__ __forceinline__ float waveReduceSum(float v) {
#pragma unroll
    for (int off = 32; off > 0; off >>= 1) v += __shfl_xor(v, off);
    return v;
}

// T1: XCD-chunked swizzle (nwg % 8 == 0 for all grids here).
__device__ __forceinline__ void swz_decode(int& x, int& y, int& z) {
    const int gx = gridDim.x, gy = gridDim.y;
    const int nwg = gx * gy * gridDim.z;
    const int fid = blockIdx.x + gx * (blockIdx.y + gy * blockIdx.z);
    const int cpx = nwg >> 3;
    int swz = (fid & 7) * cpx + (fid >> 3);
    x = swz % gx; swz /= gx;
    y = swz % gy; z = swz / gy;
}

__global__ void zero_means_kernel(float* means) {
    if (threadIdx.x < 4) means[threadIdx.x] = 0.0f;
}

// ---- stage a [128 rows][32 k] 16-bit tile into an 8 KiB LDS array via global_load_lds.
// 16B-chunk XOR swizzle: physical slot p holds logical (n=p>>2, k4=(p&3)^((n>>1)&3)).
__device__ __forceinline__ void stage_tile(const u16* __restrict__ src, int ld, int k0,
                                           u16* lds_arr, int w, int l) {
#pragma unroll
    for (int inst = 0; inst < 2; inst++) {
        const int p = w * 128 + inst * 64 + l;
        const int n = p >> 2;
        const int k4 = (p & 3) ^ ((n >> 1) & 3);
        const u16* g = src + n * ld + k0 + k4 * 8;
        u16* lp = lds_arr + (w * 128 + inst * 64) * 8;  // wave-uniform; lane adds l*16B
        __builtin_amdgcn_global_load_lds(
            (const __attribute__((address_space(1))) u32*)g,
            (__attribute__((address_space(3))) u32*)lp, 16, 0, 0);
    }
}

// ---- one 32-k MFMA block (16 MFMA) from a staged LDS pair
template<bool BF>
__device__ __forceinline__ void mfma_block(const u16* sA, const u16* sB,
                                           int wr, int wc, int fr, int kq, f32x4 acc[4][4]) {
#define SLOT(row) (((row) * 4 + ((kq) ^ (((row) >> 1) & 3))) * 8)
    if constexpr (BF) {
        bf16x8 a[4], b[4];
#pragma unroll
        for (int mi = 0; mi < 4; mi++) a[mi] = *(const bf16x8*)(sA + SLOT(wr * 64 + mi * 16 + fr));
#pragma unroll
        for (int ni = 0; ni < 4; ni++) b[ni] = *(const bf16x8*)(sB + SLOT(wc * 64 + ni * 16 + fr));
#pragma unroll
        for (int mi = 0; mi < 4; mi++)
#pragma unroll
            for (int ni = 0; ni < 4; ni++)
                acc[mi][ni] = __builtin_amdgcn_mfma_f32_16x16x32_bf16(a[mi], b[ni], acc[mi][ni], 0, 0, 0);
    } else {
        f16x8 a[4], b[4];
#pragma unroll
        for (int mi = 0; mi < 4; mi++) a[mi] = *(const f16x8*)(sA + SLOT(wr * 64 + mi * 16 + fr));
#pragma unroll
        for (int ni = 0; ni < 4; ni++) b[ni] = *(const f16x8*)(sB + SLOT(wc * 64 + ni * 16 + fr));
#pragma unroll
        for (int mi = 0; mi < 4; mi++)
#pragma unroll
            for (int ni = 0; ni < 4; ni++)
                acc[mi][ni] = __builtin_amdgcn_mfma_f32_16x16x32_f16(a[mi], b[ni], acc[mi][ni], 0, 0, 0);
    }
#undef SLOT
}

// ---- MFMA core: BK=64, single-buffered, 32 MFMA per barrier pair.
template<bool BF>
__device__ __forceinline__ void mm_core(const u16* __restrict__ A, const u16* __restrict__ B,
                                        int K, int ldA, int ldB, u16* s, f32x4 acc[4][4]) {
    const int t = threadIdx.x, w = t >> 6, l = t & 63;
    const int wr = w >> 1, wc = w & 1, fr = l & 15, kq = l >> 4;
    u16 *sA0 = s, *sA1 = s + 4096, *sB0 = s + 8192, *sB1 = s + 12288;
    for (int k0 = 0; k0 < K; k0 += 64) {
        __syncthreads();
        stage_tile(A, ldA, k0, sA0, w, l);
        stage_tile(A, ldA, k0 + 32, sA1, w, l);
        stage_tile(B, ldB, k0, sB0, w, l);
        stage_tile(B, ldB, k0 + 32, sB1, w, l);
        __syncthreads();
        mfma_block<BF>(sA0, sB0, wr, wc, fr, kq, acc);
        mfma_block<BF>(sA1, sB1, wr, wc, fr, kq, acc);
    }
}

#define ACC_INIT(acc)                                         \
    f32x4 acc[4][4];                                          \
    _Pragma("unroll") for (int mi_ = 0; mi_ < 4; mi_++)       \
    _Pragma("unroll") for (int ni_ = 0; ni_ < 4; ni_++)       \
        acc[mi_][ni_] = (f32x4){0.f, 0.f, 0.f, 0.f};

// 32 KiB for pure-GEMM kernels (cheap epilogues, half/quarter-pass).
#define SMEM_BYTES 32768

// ---- epilogue: 128x128 16-bit tile via two [64][132] LDS half-passes -> coalesced stores
template<bool BF, bool BCOL, bool BROW>
__device__ __forceinline__ void epi_h16(char* smem, const f32x4 acc[4][4],
                                        const float* biasCol, const float* biasRow,
                                        u16* O, int ldO) {
    const int t = threadIdx.x, w = t >> 6, l = t & 63;
    const int wr = w >> 1, wc = w & 1, fr = l & 15, fq = l >> 4;
    u16* sb16 = (u16*)smem;   // [64][132]
    u32* sb32 = (u32*)smem;   // [64][66]
#pragma unroll
    for (int half = 0; half < 2; half++) {
        __syncthreads();
        if (wr == half) {
#pragma unroll
            for (int ni = 0; ni < 4; ni++) {
                const int col = wc * 64 + ni * 16 + fr;
                const float bc = BCOL ? biasCol[col] : 0.0f;
#pragma unroll
                for (int mi = 0; mi < 4; mi++)
#pragma unroll
                    for (int r = 0; r < 4; r++) {
                        const int lrow = mi * 16 + fq * 4 + r;
                        const float v = acc[mi][ni][r] + bc +
                                        (BROW ? biasRow[half * 64 + lrow] : 0.0f);
                        sb16[lrow * 132 + col] = BF ? f2bf(v) : f2h(v);
                    }
            }
        }
        __syncthreads();
#pragma unroll
        for (int it = 0; it < 4; it++) {
            const int idx = it * 256 + t;       // 64 rows * 16 chunks of 16B
            const int rr = idx >> 4, ch = idx & 15;
            const uint4 v4 = *(const uint4*)&sb32[rr * 66 + ch * 4];
            *(uint4*)&O[(size_t)(half * 64 + rr) * ldO + ch * 8] = v4;
        }
    }
}

// ---- epilogue: 128x128 fp32 tile via four [32][132] LDS quarter-passes.
// inv4[ni] is a per-thread, per-output-column scale (same cols in every quarter).
template<bool SCALE>
__device__ __forceinline__ void epi_f32(char* smem, const f32x4 acc[4][4],
                                        const float* inv4, float* O, int ldO) {
    const int t = threadIdx.x, w = t >> 6, l = t & 63;
    const int wr = w >> 1, wc = w & 1, fr = l & 15, fq = l >> 4;
    float* sf = (float*)smem;  // [32][132]
#pragma unroll
    for (int q = 0; q < 4; q++) {
        __syncthreads();
        if (wr == (q >> 1)) {
            const int mi0 = (q & 1) * 2;
#pragma unroll
            for (int ni = 0; ni < 4; ni++) {
                const int col = wc * 64 + ni * 16 + fr;
                const float inv = SCALE ? inv4[ni] : 1.0f;
#pragma unroll
                for (int mm = 0; mm < 2; mm++)
#pragma unroll
                    for (int r = 0; r < 4; r++) {
                        const int lrow = mm * 16 + fq * 4 + r;
                        sf[lrow * 132 + col] = acc[mi0 + mm][ni][r] * inv;
                    }
            }
        }
        __syncthreads();
#pragma unroll
        for (int it = 0; it < 4; it++) {
            const int idx = it * 256 + t;       // 32 rows * 32 chunks of 16B
            const int rr = idx >> 5, ch = idx & 31;
            const float4 v4 = *(const float4*)&sf[rr * 132 + ch * 4];
            *(float4*)&O[(size_t)(q * 32 + rr) * ldO + ch * 4] = v4;
        }
    }
}

// ---- transpose: X fp32 [ib][C][HW]  ->  Xt fp16 [ib][HW][C]
__global__ __launch_bounds__(256) void tconv_kernel(
    const float* __restrict__ tgt, const float* __restrict__ src,
    u16* __restrict__ Tt, u16* __restrict__ St) {
    __shared__ float s[64][65];
    const int z = blockIdx.z;
    const int ib = z & 15;
    const float* X = (z >> 4 ? src : tgt) + (size_t)ib * CCH * HWN;
    u16* O = (z >> 4 ? St : Tt) + (size_t)ib * HWN * CCH;
    const int n0 = blockIdx.x * 64, c0 = blockIdx.y * 64;
    const int t = threadIdx.x;
    {
        const int cc = t >> 4, nch = (t & 15) * 4;
#pragma unroll
        for (int r = 0; r < 4; r++) {
            const float4 v = *(const float4*)&X[(size_t)(c0 + cc + r * 16) * HWN + n0 + nch];
            s[cc + r * 16][nch + 0] = v.x;
            s[cc + r * 16][nch + 1] = v.y;
            s[cc + r * 16][nch + 2] = v.z;
            s[cc + r * 16][nch + 3] = v.w;
        }
    }
    __syncthreads();
    const int nl = t >> 2;            // local row n (0..63)
    const int cb = (t & 3) * 16;      // col chunk base
    __attribute__((aligned(16))) u16 hbuf[16];
#pragma unroll
    for (int cc = 0; cc < 16; cc++) hbuf[cc] = f2h(s[cb + cc][nl]);
    const size_t orow = (size_t)(n0 + nl) * CCH + c0 + cb;
    *(uint4*)&O[orow + 0] = *(const uint4*)&hbuf[0];
    *(uint4*)&O[orow + 8] = *(const uint4*)&hbuf[8];
}

// ---- weights fp32 -> fp16
__global__ __launch_bounds__(256) void convw_kernel(
    const float* __restrict__ Wq, const float* __restrict__ Wk, const float* __restrict__ Wv,
    u16* __restrict__ Wqh, u16* __restrict__ Wkh, u16* __restrict__ Wvh) {
    const int idx = (blockIdx.x * 256 + threadIdx.x) * 4;  // over NUMH*C*C = 524288
    {
        const float4 v = *(const float4*)&Wq[idx];
        uint2 h = {(u32)f2h(v.x) | ((u32)f2h(v.y) << 16), (u32)f2h(v.z) | ((u32)f2h(v.w) << 16)};
        *(uint2*)&Wqh[idx] = h;
    }
    {
        const float4 v = *(const float4*)&Wk[idx];
        uint2 h = {(u32)f2h(v.x) | ((u32)f2h(v.y) << 16), (u32)f2h(v.z) | ((u32)f2h(v.w) << 16)};
        *(uint2*)&Wkh[idx] = h;
    }
    {
        const float4 v = *(const float4*)&Wv[idx];
        uint2 h = {(u32)f2h(v.x) | ((u32)f2h(v.y) << 16), (u32)f2h(v.z) | ((u32)f2h(v.w) << 16)};
        *(uint2*)&Wvh[idx] = h;
    }
}

// ---- Q/K projection: D[n][o] = sum_c Xt[n][c]*W[o][c] + bias[o], fp16 out
__global__ __launch_bounds__(256) void proj_qk_kernel(
    const u16* __restrict__ Tt, const u16* __restrict__ St,
    const u16* __restrict__ Wqh, const u16* __restrict__ Wkh,
    const float* __restrict__ bq, const float* __restrict__ bk,
    u16* __restrict__ Qp, u16* __restrict__ Kp) {
    __shared__ __align__(16) char smem[SMEM_BYTES];
    int bx, by, z;
    swz_decode(bx, by, z);
    const int b = z & 7, i = (z >> 3) & 1, p = z >> 4;
    const size_t ib = (size_t)(i * BATCH + b) * HWN * CCH;
    const u16* A = (p ? St : Tt) + ib;
    const u16* B = (p ? Wkh : Wqh) + (size_t)i * CCH * CCH;
    const float* bias = (p ? bk : bq) + i * CCH;
    u16* O = (p ? Kp : Qp) + ib;
    const int tile_m = by * 128, tile_n = bx * 128;

    ACC_INIT(acc)
    mm_core<false>(A + (size_t)tile_m * CCH, B + (size_t)tile_n * CCH,
                   CCH, CCH, CCH, (u16*)smem, acc);

    epi_h16<false, true, false>(smem, acc, bias + tile_n, nullptr,
                                O + (size_t)tile_m * CCH + tile_n, CCH);
}

// ---- V projection: D[c][n] = sum_cin Wv[c][cin]*Xt[n][cin] + bv[c], bf16 out
__global__ __launch_bounds__(256) void proj_v_kernel(
    const u16* __restrict__ Wvh, const u16* __restrict__ Tt,
    const float* __restrict__ bvv, u16* __restrict__ Vb) {
    __shared__ __align__(16) char smem[SMEM_BYTES];
    int bx, by, z;
    swz_decode(bx, by, z);
    const int b = z & 7, i = z >> 3;
    const size_t ib = (size_t)(i * BATCH + b) * HWN * CCH;
    const u16* A = Wvh + (size_t)i * CCH * CCH;
    const u16* B = Tt + ib;
    const int tile_m = by * 128, tile_n = bx * 128;

    ACC_INIT(acc)
    mm_core<false>(A + (size_t)tile_m * CCH, B + (size_t)tile_n * CCH,
                   CCH, CCH, CCH, (u16*)smem, acc);

    u16* Ov = Vb + (size_t)(i * BATCH + b) * CCH * HWN;
    epi_h16<true, false, true>(smem, acc, nullptr, bvv + i * CCH + tile_m,
                               Ov + (size_t)tile_m * HWN + tile_n, HWN);
}

// ---- energy fused: P~[n][m] = exp(sum_c Q[n][c]*K[m][c]) bf16; per-block rowsum
// partials (non-atomic, slot = bx*2+wc) + means atomics.
// Full-parallel [128][132] epilogue (all 4 waves convert simultaneously) — the
// R8 half-pass version serialized the exp work 2x and cost +20 us.
__global__ __launch_bounds__(256) void gemmE_kernel(
    const u16* __restrict__ Qp, const u16* __restrict__ Kp,
    u16* __restrict__ P, float* __restrict__ rs, float* __restrict__ means,
    int b0, int Bc) {
    __shared__ __align__(16) char smem[33792];
    __shared__ float redsum[4];
    int bx, by, z;
    swz_decode(bx, by, z);
    const int j = z & 1, ib2 = z >> 1;
    const int i = ib2 / Bc, bb = ib2 % Bc, b = b0 + bb;
    const size_t offA = (size_t)(i * BATCH + b) * HWN * CCH;
    const size_t offB = (size_t)(j * BATCH + b) * HWN * CCH;
    const int tile_m = by * 128, tile_n = bx * 128;
    u16* Po = P + (size_t)(ib2 * 2 + j) * HWN * HWN + (size_t)tile_m * HWN + tile_n;

    ACC_INIT(acc)
    mm_core<false>(Qp + offA + (size_t)tile_m * CCH, Kp + offB + (size_t)tile_n * CCH,
                   CCH, CCH, CCH, (u16*)smem, acc);

    const int t = threadIdx.x, w = t >> 6, l = t & 63;
    const int wr = w >> 1, wc = w & 1, fr = l & 15, fq = l >> 4;
    u16* sb16 = (u16*)smem;   // [128][132]
    u32* sb32 = (u32*)smem;   // [128][66]
    float* rsp = rs + ((size_t)(ib2 * 2 + j) * 16 + (bx * 2 + wc)) * HWN;
    __syncthreads();
    float tsum = 0.0f;
    float rowacc[4][4];
#pragma unroll
    for (int mi = 0; mi < 4; mi++)
#pragma unroll
        for (int r = 0; r < 4; r++) rowacc[mi][r] = 0.0f;
#pragma unroll
    for (int ni = 0; ni < 4; ni++) {
        const int col = wc * 64 + ni * 16 + fr;
#pragma unroll
        for (int mi = 0; mi < 4; mi++)
#pragma unroll
            for (int r = 0; r < 4; r++) {
                const int row = wr * 64 + mi * 16 + fq * 4 + r;
                const float raw = acc[mi][ni][r];
                tsum += raw;
                const float ex = __expf(raw);
                rowacc[mi][r] += ex;
                sb16[row * 132 + col] = f2bf(ex);
            }
    }
    // means partial (raw E sum)
    tsum = waveReduceSum(tsum);
    if (l == 0) redsum[w] = tsum;
    // per-row exp sums: reduce across the 16 fr lanes, write this (bx,wc) partial
#pragma unroll
    for (int mi = 0; mi < 4; mi++)
#pragma unroll
        for (int r = 0; r < 4; r++) {
            float v = rowacc[mi][r];
            v += __shfl_xor(v, 1); v += __shfl_xor(v, 2);
            v += __shfl_xor(v, 4); v += __shfl_xor(v, 8);
            if (fr == 0) rsp[tile_m + wr * 64 + mi * 16 + fq * 4 + r] = v;
        }
    __syncthreads();
    if (t == 0) atomicAdd(&means[i * 2 + j], redsum[0] + redsum[1] + redsum[2] + redsum[3]);
    // coalesced P~ store
#pragma unroll
    for (int it = 0; it < 8; it++) {
        const int idx = it * 256 + t;
        const int rr = idx >> 4, ch = idx & 15;
        const uint4 v4 = *(const uint4*)&sb32[rr * 66 + ch * 4];
        *(uint4*)&Po[(size_t)rr * HWN + ch * 8] = v4;
    }
}

// ---- out[c][n] = (A0*(l1/l0) + A1)/l1 where Aj = sum_m V[c][m]*P~j[n][m];
// l_j[n] = sum of 16 per-block partials in rs.
__global__ __launch_bounds__(256) void gemmOut_kernel(
    const u16* __restrict__ Vb, const u16* __restrict__ P, const float* __restrict__ rs,
    float* __restrict__ outp, int b0, int Bc) {
    __shared__ __align__(16) char smem[SMEM_BYTES];
    int bx, by, ib2;
    swz_decode(bx, by, ib2);
    const int i = ib2 / Bc, bb = ib2 % Bc, b = b0 + bb;
    const u16* A = Vb + (size_t)(i * BATCH + b) * CCH * HWN;
    const u16* P0 = P + (size_t)(ib2 * 2 + 0) * HWN * HWN;
    const u16* P1 = P + (size_t)(ib2 * 2 + 1) * HWN * HWN;
    const float* rs0p = rs + (size_t)(ib2 * 2 + 0) * 16 * HWN;
    const float* rs1p = rs + (size_t)(ib2 * 2 + 1) * 16 * HWN;
    float* O = outp + (size_t)(i * BATCH + b) * CCH * HWN;
    const int tile_m = by * 128, tile_n = bx * 128;
    const int t = threadIdx.x, w = t >> 6, l = t & 63;
    const int wc = w & 1, fr = l & 15;

    // per-thread column scales: sc = l1/l0 (mid-rescale), inv4 = 1/l1 (final)
    float sc[4], inv4[4];
#pragma unroll
    for (int ni = 0; ni < 4; ni++) {
        const int col = tile_n + wc * 64 + ni * 16 + fr;
        float s0 = 0.0f, s1 = 0.0f;
#pragma unroll
        for (int sl = 0; sl < 16; sl++) {
            s0 += rs0p[sl * HWN + col];
            s1 += rs1p[sl * HWN + col];
        }
        sc[ni] = s1 / s0;
        inv4[ni] = 1.0f / s1;
    }

    ACC_INIT(acc)
    mm_core<true>(A + (size_t)tile_m * HWN, P0 + (size_t)tile_n * HWN,
                  HWN, HWN, HWN, (u16*)smem, acc);
#pragma unroll
    for (int ni = 0; ni < 4; ni++)
#pragma unroll
        for (int mi = 0; mi < 4; mi++) acc[mi][ni] *= sc[ni];
    mm_core<true>(A + (size_t)tile_m * HWN, P1 + (size_t)tile_n * HWN,
                  HWN, HWN, HWN, (u16*)smem, acc);

    epi_f32<true>(smem, acc, inv4, O + (size_t)tile_m * HWN + tile_n, HWN);
}

__global__ void alphas_kernel(const float* __restrict__ means, float* __restrict__ outp) {
    if (threadIdx.x != 0) return;
    const float cnt = (float)BATCH * (float)HWN * (float)HWN;
    float m[4];
#pragma unroll
    for (int k = 0; k < 4; k++) m[k] = means[k] / cnt;
#pragma unroll
    for (int i = 0; i < 2; i++) {
        const float a = m[i * 2 + 0], bsc = m[i * 2 + 1];
        const float mx = fmaxf(a, bsc);
        const float ea = __expf(a - mx), eb = __expf(bsc - mx);
        const float inv = 1.0f / (ea + eb);
        outp[i * 2 + 0] = ea * inv;
        outp[i * 2 + 1] = eb * inv;
    }
}

extern "C" void kernel_launch(void* const* d_in, const int* in_sizes, int n_in,
                              void* d_out, int out_size, void* d_ws, size_t ws_size,
                              hipStream_t stream) {
    const float* fsrc = (const float*)d_in[0];
    const float* ftgt = (const float*)d_in[1];
    const float* Wq = (const float*)d_in[2];
    const float* bq = (const float*)d_in[3];
    const float* Wk = (const float*)d_in[4];
    const float* bk = (const float*)d_in[5];
    const float* Wv = (const float*)d_in[6];
    const float* bv = (const float*)d_in[7];
    float* outp = (float*)d_out;

    const size_t SZ_ACT = (size_t)NUMH * BATCH * HWN * CCH * 2;  // 16 MiB 16-bit
    const size_t SZ_W = (size_t)NUMH * CCH * CCH * 2;            // 1 MiB 16-bit
    char* w = (char*)d_ws;
    u16* Qp = (u16*)w; w += SZ_ACT;
    u16* Kp = (u16*)w; w += SZ_ACT;
    u16* Vb = (u16*)w; w += SZ_ACT;
    u16* Wqh = (u16*)w; w += SZ_W;
    u16* Wkh = (u16*)w; w += SZ_W;
    u16* Wvh = (u16*)w; w += SZ_W;
    float* means = (float*)w; w += 64;
    float* rs = (float*)w; w += (size_t)NUMH * BATCH * 2 * 16 * HWN * 4;  // rowsum partials
    char* region = w;  // transpose buffers live here early; P~ overlays later
    u16* Tt = (u16*)region;
    u16* St = (u16*)(region + SZ_ACT);

    const size_t base_used = (size_t)(region - (char*)d_ws);
    int Bc = 8;
    while (Bc > 1) {
        size_t need = (size_t)NUMH * Bc * 2 * HWN * HWN * 2;  // P~ bf16
        size_t tneed = need > 2 * SZ_ACT ? need : 2 * SZ_ACT;
        if (base_used + tneed <= ws_size) break;
        Bc >>= 1;
    }
    u16* P = (u16*)region;

    zero_means_kernel<<<1, 64, 0, stream>>>(means);
    convw_kernel<<<512, 256, 0, stream>>>(Wq, Wk, Wv, Wqh, Wkh, Wvh);
    tconv_kernel<<<dim3(16, 8, 32), 256, 0, stream>>>(ftgt, fsrc, Tt, St);
    proj_qk_kernel<<<dim3(4, 8, 32), 256, 0, stream>>>(Tt, St, Wqh, Wkh, bq, bk, Qp, Kp);
    proj_v_kernel<<<dim3(8, 4, 16), 256, 0, stream>>>(Wvh, Tt, bv, Vb);

    const int nch = BATCH / Bc;
    for (int ch = 0; ch < nch; ch++) {
        const int b0 = ch * Bc;
        gemmE_kernel<<<dim3(8, 8, NUMH * Bc * 2), 256, 0, stream>>>(Qp, Kp, P, rs, means, b0, Bc);
        gemmOut_kernel<<<dim3(8, 4, NUMH * Bc), 256, 0, stream>>>(Vb, P, rs, outp, b0, Bc);
    }
    alphas_kernel<<<1, 1, 0, stream>>>(means, outp + (out_size - 4));
}

// Round 10
// 189.779 us; speedup vs baseline: 1.1553x; 1.1553x over previous
//
#include <hip/hip_runtime.h>

#define NUMH 2
#define BATCH 8
#define CCH 512
#define HWN 1024

typedef unsigned short u16;
typedef unsigned int u32;
typedef _Float16 f16;
typedef __attribute__((ext_vector_type(8))) _Float16 f16x8;
typedef __attribute__((ext_vector_type(8))) short bf16x8;
typedef __attribute__((ext_vector_type(4))) float f32x4;

__device__ __forceinline__ u16 f2h(float x) {
    union { f16 h; u16 u; } cv;
    cv.h = (f16)x;
    return cv.u;
}
__device__ __forceinline__ u16 f2bf(float x) {
    u32 u = __float_as_uint(x);
    return (u16)((u + 0x7fffu + ((u >> 16) & 1u)) >> 16);
}

__device__ __forceinline__ float waveReduceSum(float v) {
#pragma unroll
    for (int off = 32; off > 0; off >>= 1) v += __shfl_xor(v, off);
    return v;
}

// T1: XCD-chunked swizzle (nwg % 8 == 0 for all grids here).
__device__ __forceinline__ void swz_decode(int& x, int& y, int& z) {
    const int gx = gridDim.x, gy = gridDim.y;
    const int nwg = gx * gy * gridDim.z;
    const int fid = blockIdx.x + gx * (blockIdx.y + gy * blockIdx.z);
    const int cpx = nwg >> 3;
    int swz = (fid & 7) * cpx + (fid >> 3);
    x = swz % gx; swz /= gx;
    y = swz % gy; z = swz / gy;
}

__global__ void zero_means_kernel(float* means) {
    if (threadIdx.x < 4) means[threadIdx.x] = 0.0f;
}

// ---- reduce 16 rowsum partials -> ls (one float per (slice, col))
__global__ __launch_bounds__(256) void reduce_rs_kernel(const float* __restrict__ rs,
                                                        float* __restrict__ ls, int n) {
    const int idx = blockIdx.x * 256 + threadIdx.x;   // slice*HWN + col
    if (idx >= n) return;
    const int slice = idx >> 10, col = idx & 1023;
    const float* p = rs + ((size_t)slice * 16) * HWN + col;
    float s = 0.0f;
#pragma unroll
    for (int k = 0; k < 16; k++) s += p[k * HWN];
    ls[idx] = s;
}

// ---- stage a [128 rows][32 k] 16-bit tile into an 8 KiB LDS array via global_load_lds.
// 16B-chunk XOR swizzle: physical slot p holds logical (n=p>>2, k4=(p&3)^((n>>1)&3)).
__device__ __forceinline__ void stage_tile(const u16* __restrict__ src, int ld, int k0,
                                           u16* lds_arr, int w, int l) {
#pragma unroll
    for (int inst = 0; inst < 2; inst++) {
        const int p = w * 128 + inst * 64 + l;
        const int n = p >> 2;
        const int k4 = (p & 3) ^ ((n >> 1) & 3);
        const u16* g = src + n * ld + k0 + k4 * 8;
        u16* lp = lds_arr + (w * 128 + inst * 64) * 8;  // wave-uniform; lane adds l*16B
        __builtin_amdgcn_global_load_lds(
            (const __attribute__((address_space(1))) u32*)g,
            (__attribute__((address_space(3))) u32*)lp, 16, 0, 0);
    }
}

// ---- one 32-k MFMA block (16 MFMA) from a staged LDS pair
template<bool BF>
__device__ __forceinline__ void mfma_block(const u16* sA, const u16* sB,
                                           int wr, int wc, int fr, int kq, f32x4 acc[4][4]) {
#define SLOT(row) (((row) * 4 + ((kq) ^ (((row) >> 1) & 3))) * 8)
    if constexpr (BF) {
        bf16x8 a[4], b[4];
#pragma unroll
        for (int mi = 0; mi < 4; mi++) a[mi] = *(const bf16x8*)(sA + SLOT(wr * 64 + mi * 16 + fr));
#pragma unroll
        for (int ni = 0; ni < 4; ni++) b[ni] = *(const bf16x8*)(sB + SLOT(wc * 64 + ni * 16 + fr));
#pragma unroll
        for (int mi = 0; mi < 4; mi++)
#pragma unroll
            for (int ni = 0; ni < 4; ni++)
                acc[mi][ni] = __builtin_amdgcn_mfma_f32_16x16x32_bf16(a[mi], b[ni], acc[mi][ni], 0, 0, 0);
    } else {
        f16x8 a[4], b[4];
#pragma unroll
        for (int mi = 0; mi < 4; mi++) a[mi] = *(const f16x8*)(sA + SLOT(wr * 64 + mi * 16 + fr));
#pragma unroll
        for (int ni = 0; ni < 4; ni++) b[ni] = *(const f16x8*)(sB + SLOT(wc * 64 + ni * 16 + fr));
#pragma unroll
        for (int mi = 0; mi < 4; mi++)
#pragma unroll
            for (int ni = 0; ni < 4; ni++)
                acc[mi][ni] = __builtin_amdgcn_mfma_f32_16x16x32_f16(a[mi], b[ni], acc[mi][ni], 0, 0, 0);
    }
#undef SLOT
}

// ---- MFMA core: BK=64, single-buffered, 32 MFMA per barrier pair.
template<bool BF>
__device__ __forceinline__ void mm_core(const u16* __restrict__ A, const u16* __restrict__ B,
                                        int K, int ldA, int ldB, u16* s, f32x4 acc[4][4]) {
    const int t = threadIdx.x, w = t >> 6, l = t & 63;
    const int wr = w >> 1, wc = w & 1, fr = l & 15, kq = l >> 4;
    u16 *sA0 = s, *sA1 = s + 4096, *sB0 = s + 8192, *sB1 = s + 12288;
    for (int k0 = 0; k0 < K; k0 += 64) {
        __syncthreads();
        stage_tile(A, ldA, k0, sA0, w, l);
        stage_tile(A, ldA, k0 + 32, sA1, w, l);
        stage_tile(B, ldB, k0, sB0, w, l);
        stage_tile(B, ldB, k0 + 32, sB1, w, l);
        __syncthreads();
        mfma_block<BF>(sA0, sB0, wr, wc, fr, kq, acc);
        mfma_block<BF>(sA1, sB1, wr, wc, fr, kq, acc);
    }
}

#define ACC_INIT(acc)                                         \
    f32x4 acc[4][4];                                          \
    _Pragma("unroll") for (int mi_ = 0; mi_ < 4; mi_++)       \
    _Pragma("unroll") for (int ni_ = 0; ni_ < 4; ni_++)       \
        acc[mi_][ni_] = (f32x4){0.f, 0.f, 0.f, 0.f};

// 32 KiB for pure-GEMM kernels (cheap epilogues, half/quarter-pass).
#define SMEM_BYTES 32768

// ---- epilogue: 128x128 16-bit tile via two [64][132] LDS half-passes -> coalesced stores
template<bool BF, bool BCOL, bool BROW>
__device__ __forceinline__ void epi_h16(char* smem, const f32x4 acc[4][4],
                                        const float* biasCol, const float* biasRow,
                                        u16* O, int ldO) {
    const int t = threadIdx.x, w = t >> 6, l = t & 63;
    const int wr = w >> 1, wc = w & 1, fr = l & 15, fq = l >> 4;
    u16* sb16 = (u16*)smem;   // [64][132]
    u32* sb32 = (u32*)smem;   // [64][66]
#pragma unroll
    for (int half = 0; half < 2; half++) {
        __syncthreads();
        if (wr == half) {
#pragma unroll
            for (int ni = 0; ni < 4; ni++) {
                const int col = wc * 64 + ni * 16 + fr;
                const float bc = BCOL ? biasCol[col] : 0.0f;
#pragma unroll
                for (int mi = 0; mi < 4; mi++)
#pragma unroll
                    for (int r = 0; r < 4; r++) {
                        const int lrow = mi * 16 + fq * 4 + r;
                        const float v = acc[mi][ni][r] + bc +
                                        (BROW ? biasRow[half * 64 + lrow] : 0.0f);
                        sb16[lrow * 132 + col] = BF ? f2bf(v) : f2h(v);
                    }
            }
        }
        __syncthreads();
#pragma unroll
        for (int it = 0; it < 4; it++) {
            const int idx = it * 256 + t;       // 64 rows * 16 chunks of 16B
            const int rr = idx >> 4, ch = idx & 15;
            const uint4 v4 = *(const uint4*)&sb32[rr * 66 + ch * 4];
            *(uint4*)&O[(size_t)(half * 64 + rr) * ldO + ch * 8] = v4;
        }
    }
}

// ---- epilogue: 128x128 fp32 tile via four [32][132] LDS quarter-passes.
// SCALE: multiply column col by 1/ls[col] (ls read inside, nothing live across GEMM).
template<bool SCALE>
__device__ __forceinline__ void epi_f32(char* smem, const f32x4 acc[4][4],
                                        const float* ls, float* O, int ldO) {
    const int t = threadIdx.x, w = t >> 6, l = t & 63;
    const int wr = w >> 1, wc = w & 1, fr = l & 15, fq = l >> 4;
    float* sf = (float*)smem;  // [32][132]
#pragma unroll
    for (int q = 0; q < 4; q++) {
        __syncthreads();
        if (wr == (q >> 1)) {
            const int mi0 = (q & 1) * 2;
#pragma unroll
            for (int ni = 0; ni < 4; ni++) {
                const int col = wc * 64 + ni * 16 + fr;
                const float inv = SCALE ? 1.0f / ls[col] : 1.0f;
#pragma unroll
                for (int mm = 0; mm < 2; mm++)
#pragma unroll
                    for (int r = 0; r < 4; r++) {
                        const int lrow = mm * 16 + fq * 4 + r;
                        sf[lrow * 132 + col] = acc[mi0 + mm][ni][r] * inv;
                    }
            }
        }
        __syncthreads();
#pragma unroll
        for (int it = 0; it < 4; it++) {
            const int idx = it * 256 + t;       // 32 rows * 32 chunks of 16B
            const int rr = idx >> 5, ch = idx & 31;
            const float4 v4 = *(const float4*)&sf[rr * 132 + ch * 4];
            *(float4*)&O[(size_t)(q * 32 + rr) * ldO + ch * 4] = v4;
        }
    }
}

// ---- transpose: X fp32 [ib][C][HW]  ->  Xt fp16 [ib][HW][C]
__global__ __launch_bounds__(256) void tconv_kernel(
    const float* __restrict__ tgt, const float* __restrict__ src,
    u16* __restrict__ Tt, u16* __restrict__ St) {
    __shared__ float s[64][65];
    const int z = blockIdx.z;
    const int ib = z & 15;
    const float* X = (z >> 4 ? src : tgt) + (size_t)ib * CCH * HWN;
    u16* O = (z >> 4 ? St : Tt) + (size_t)ib * HWN * CCH;
    const int n0 = blockIdx.x * 64, c0 = blockIdx.y * 64;
    const int t = threadIdx.x;
    {
        const int cc = t >> 4, nch = (t & 15) * 4;
#pragma unroll
        for (int r = 0; r < 4; r++) {
            const float4 v = *(const float4*)&X[(size_t)(c0 + cc + r * 16) * HWN + n0 + nch];
            s[cc + r * 16][nch + 0] = v.x;
            s[cc + r * 16][nch + 1] = v.y;
            s[cc + r * 16][nch + 2] = v.z;
            s[cc + r * 16][nch + 3] = v.w;
        }
    }
    __syncthreads();
    const int nl = t >> 2;            // local row n (0..63)
    const int cb = (t & 3) * 16;      // col chunk base
    __attribute__((aligned(16))) u16 hbuf[16];
#pragma unroll
    for (int cc = 0; cc < 16; cc++) hbuf[cc] = f2h(s[cb + cc][nl]);
    const size_t orow = (size_t)(n0 + nl) * CCH + c0 + cb;
    *(uint4*)&O[orow + 0] = *(const uint4*)&hbuf[0];
    *(uint4*)&O[orow + 8] = *(const uint4*)&hbuf[8];
}

// ---- weights fp32 -> fp16
__global__ __launch_bounds__(256) void convw_kernel(
    const float* __restrict__ Wq, const float* __restrict__ Wk, const float* __restrict__ Wv,
    u16* __restrict__ Wqh, u16* __restrict__ Wkh, u16* __restrict__ Wvh) {
    const int idx = (blockIdx.x * 256 + threadIdx.x) * 4;  // over NUMH*C*C = 524288
    {
        const float4 v = *(const float4*)&Wq[idx];
        uint2 h = {(u32)f2h(v.x) | ((u32)f2h(v.y) << 16), (u32)f2h(v.z) | ((u32)f2h(v.w) << 16)};
        *(uint2*)&Wqh[idx] = h;
    }
    {
        const float4 v = *(const float4*)&Wk[idx];
        uint2 h = {(u32)f2h(v.x) | ((u32)f2h(v.y) << 16), (u32)f2h(v.z) | ((u32)f2h(v.w) << 16)};
        *(uint2*)&Wkh[idx] = h;
    }
    {
        const float4 v = *(const float4*)&Wv[idx];
        uint2 h = {(u32)f2h(v.x) | ((u32)f2h(v.y) << 16), (u32)f2h(v.z) | ((u32)f2h(v.w) << 16)};
        *(uint2*)&Wvh[idx] = h;
    }
}

// ---- Q/K projection: D[n][o] = sum_c Xt[n][c]*W[o][c] + bias[o], fp16 out
__global__ __launch_bounds__(256) void proj_qk_kernel(
    const u16* __restrict__ Tt, const u16* __restrict__ St,
    const u16* __restrict__ Wqh, const u16* __restrict__ Wkh,
    const float* __restrict__ bq, const float* __restrict__ bk,
    u16* __restrict__ Qp, u16* __restrict__ Kp) {
    __shared__ __align__(16) char smem[SMEM_BYTES];
    int bx, by, z;
    swz_decode(bx, by, z);
    const int b = z & 7, i = (z >> 3) & 1, p = z >> 4;
    const size_t ib = (size_t)(i * BATCH + b) * HWN * CCH;
    const u16* A = (p ? St : Tt) + ib;
    const u16* B = (p ? Wkh : Wqh) + (size_t)i * CCH * CCH;
    const float* bias = (p ? bk : bq) + i * CCH;
    u16* O = (p ? Kp : Qp) + ib;
    const int tile_m = by * 128, tile_n = bx * 128;

    ACC_INIT(acc)
    mm_core<false>(A + (size_t)tile_m * CCH, B + (size_t)tile_n * CCH,
                   CCH, CCH, CCH, (u16*)smem, acc);

    epi_h16<false, true, false>(smem, acc, bias + tile_n, nullptr,
                                O + (size_t)tile_m * CCH + tile_n, CCH);
}

// ---- V projection: D[c][n] = sum_cin Wv[c][cin]*Xt[n][cin] + bv[c], bf16 out
__global__ __launch_bounds__(256) void proj_v_kernel(
    const u16* __restrict__ Wvh, const u16* __restrict__ Tt,
    const float* __restrict__ bvv, u16* __restrict__ Vb) {
    __shared__ __align__(16) char smem[SMEM_BYTES];
    int bx, by, z;
    swz_decode(bx, by, z);
    const int b = z & 7, i = z >> 3;
    const size_t ib = (size_t)(i * BATCH + b) * HWN * CCH;
    const u16* A = Wvh + (size_t)i * CCH * CCH;
    const u16* B = Tt + ib;
    const int tile_m = by * 128, tile_n = bx * 128;

    ACC_INIT(acc)
    mm_core<false>(A + (size_t)tile_m * CCH, B + (size_t)tile_n * CCH,
                   CCH, CCH, CCH, (u16*)smem, acc);

    u16* Ov = Vb + (size_t)(i * BATCH + b) * CCH * HWN;
    epi_h16<true, false, true>(smem, acc, nullptr, bvv + i * CCH + tile_m,
                               Ov + (size_t)tile_m * HWN + tile_n, HWN);
}

// ---- energy fused: P~[n][m] = exp(sum_c Q[n][c]*K[m][c]) bf16; per-block rowsum
// partials (non-atomic, slot = bx*2+wc) + means atomics. Full-parallel epilogue.
__global__ __launch_bounds__(256) void gemmE_kernel(
    const u16* __restrict__ Qp, const u16* __restrict__ Kp,
    u16* __restrict__ P, float* __restrict__ rs, float* __restrict__ means,
    int b0, int Bc) {
    __shared__ __align__(16) char smem[33792];
    __shared__ float redsum[4];
    int bx, by, z;
    swz_decode(bx, by, z);
    const int j = z & 1, ib2 = z >> 1;
    const int i = ib2 / Bc, bb = ib2 % Bc, b = b0 + bb;
    const size_t offA = (size_t)(i * BATCH + b) * HWN * CCH;
    const size_t offB = (size_t)(j * BATCH + b) * HWN * CCH;
    const int tile_m = by * 128, tile_n = bx * 128;
    u16* Po = P + (size_t)(ib2 * 2 + j) * HWN * HWN + (size_t)tile_m * HWN + tile_n;

    ACC_INIT(acc)
    mm_core<false>(Qp + offA + (size_t)tile_m * CCH, Kp + offB + (size_t)tile_n * CCH,
                   CCH, CCH, CCH, (u16*)smem, acc);

    const int t = threadIdx.x, w = t >> 6, l = t & 63;
    const int wr = w >> 1, wc = w & 1, fr = l & 15, fq = l >> 4;
    u16* sb16 = (u16*)smem;   // [128][132]
    u32* sb32 = (u32*)smem;   // [128][66]
    float* rsp = rs + ((size_t)(ib2 * 2 + j) * 16 + (bx * 2 + wc)) * HWN;
    __syncthreads();
    float tsum = 0.0f;
    float rowacc[4][4];
#pragma unroll
    for (int mi = 0; mi < 4; mi++)
#pragma unroll
        for (int r = 0; r < 4; r++) rowacc[mi][r] = 0.0f;
#pragma unroll
    for (int ni = 0; ni < 4; ni++) {
        const int col = wc * 64 + ni * 16 + fr;
#pragma unroll
        for (int mi = 0; mi < 4; mi++)
#pragma unroll
            for (int r = 0; r < 4; r++) {
                const int row = wr * 64 + mi * 16 + fq * 4 + r;
                const float raw = acc[mi][ni][r];
                tsum += raw;
                const float ex = __expf(raw);
                rowacc[mi][r] += ex;
                sb16[row * 132 + col] = f2bf(ex);
            }
    }
    // means partial (raw E sum)
    tsum = waveReduceSum(tsum);
    if (l == 0) redsum[w] = tsum;
    // per-row exp sums: reduce across the 16 fr lanes, write this (bx,wc) partial
#pragma unroll
    for (int mi = 0; mi < 4; mi++)
#pragma unroll
        for (int r = 0; r < 4; r++) {
            float v = rowacc[mi][r];
            v += __shfl_xor(v, 1); v += __shfl_xor(v, 2);
            v += __shfl_xor(v, 4); v += __shfl_xor(v, 8);
            if (fr == 0) rsp[tile_m + wr * 64 + mi * 16 + fq * 4 + r] = v;
        }
    __syncthreads();
    if (t == 0) atomicAdd(&means[i * 2 + j], redsum[0] + redsum[1] + redsum[2] + redsum[3]);
    // coalesced P~ store
#pragma unroll
    for (int it = 0; it < 8; it++) {
        const int idx = it * 256 + t;
        const int rr = idx >> 4, ch = idx & 15;
        const uint4 v4 = *(const uint4*)&sb32[rr * 66 + ch * 4];
        *(uint4*)&Po[(size_t)rr * HWN + ch * 8] = v4;
    }
}

// ---- out[c][n] = (A0*(l1/l0) + A1)/l1, Aj = sum_m V[c][m]*P~j[n][m]; ls pre-reduced.
__global__ __launch_bounds__(256) void gemmOut_kernel(
    const u16* __restrict__ Vb, const u16* __restrict__ P, const float* __restrict__ ls,
    float* __restrict__ outp, int b0, int Bc) {
    __shared__ __align__(16) char smem[SMEM_BYTES];
    int bx, by, ib2;
    swz_decode(bx, by, ib2);
    const int i = ib2 / Bc, bb = ib2 % Bc, b = b0 + bb;
    const u16* A = Vb + (size_t)(i * BATCH + b) * CCH * HWN;
    const u16* P0 = P + (size_t)(ib2 * 2 + 0) * HWN * HWN;
    const u16* P1 = P + (size_t)(ib2 * 2 + 1) * HWN * HWN;
    const float* ls0 = ls + (size_t)(ib2 * 2 + 0) * HWN;
    const float* ls1 = ls + (size_t)(ib2 * 2 + 1) * HWN;
    float* O = outp + (size_t)(i * BATCH + b) * CCH * HWN;
    const int tile_m = by * 128, tile_n = bx * 128;
    const int t = threadIdx.x, w = t >> 6, l = t & 63;
    const int wc = w & 1, fr = l & 15;

    ACC_INIT(acc)
    mm_core<true>(A + (size_t)tile_m * HWN, P0 + (size_t)tile_n * HWN,
                  HWN, HWN, HWN, (u16*)smem, acc);
    // rescale acc *= l1[n]/l0[n] — computed here, consumed immediately (no long live range)
#pragma unroll
    for (int ni = 0; ni < 4; ni++) {
        const int col = tile_n + wc * 64 + ni * 16 + fr;
        const float sc = ls1[col] / ls0[col];
#pragma unroll
        for (int mi = 0; mi < 4; mi++) acc[mi][ni] *= sc;
    }
    mm_core<true>(A + (size_t)tile_m * HWN, P1 + (size_t)tile_n * HWN,
                  HWN, HWN, HWN, (u16*)smem, acc);

    epi_f32<true>(smem, acc, ls1 + tile_n, O + (size_t)tile_m * HWN + tile_n, HWN);
}

__global__ void alphas_kernel(const float* __restrict__ means, float* __restrict__ outp) {
    if (threadIdx.x != 0) return;
    const float cnt = (float)BATCH * (float)HWN * (float)HWN;
    float m[4];
#pragma unroll
    for (int k = 0; k < 4; k++) m[k] = means[k] / cnt;
#pragma unroll
    for (int i = 0; i < 2; i++) {
        const float a = m[i * 2 + 0], bsc = m[i * 2 + 1];
        const float mx = fmaxf(a, bsc);
        const float ea = __expf(a - mx), eb = __expf(bsc - mx);
        const float inv = 1.0f / (ea + eb);
        outp[i * 2 + 0] = ea * inv;
        outp[i * 2 + 1] = eb * inv;
    }
}

extern "C" void kernel_launch(void* const* d_in, const int* in_sizes, int n_in,
                              void* d_out, int out_size, void* d_ws, size_t ws_size,
                              hipStream_t stream) {
    const float* fsrc = (const float*)d_in[0];
    const float* ftgt = (const float*)d_in[1];
    const float* Wq = (const float*)d_in[2];
    const float* bq = (const float*)d_in[3];
    const float* Wk = (const float*)d_in[4];
    const float* bk = (const float*)d_in[5];
    const float* Wv = (const float*)d_in[6];
    const float* bv = (const float*)d_in[7];
    float* outp = (float*)d_out;

    const size_t SZ_ACT = (size_t)NUMH * BATCH * HWN * CCH * 2;  // 16 MiB 16-bit
    const size_t SZ_W = (size_t)NUMH * CCH * CCH * 2;            // 1 MiB 16-bit
    char* w = (char*)d_ws;
    u16* Qp = (u16*)w; w += SZ_ACT;
    u16* Kp = (u16*)w; w += SZ_ACT;
    u16* Vb = (u16*)w; w += SZ_ACT;
    u16* Wqh = (u16*)w; w += SZ_W;
    u16* Wkh = (u16*)w; w += SZ_W;
    u16* Wvh = (u16*)w; w += SZ_W;
    float* means = (float*)w; w += 64;
    float* rs = (float*)w; w += (size_t)NUMH * BATCH * 2 * 16 * HWN * 4;  // rowsum partials
    float* ls = (float*)w; w += (size_t)NUMH * BATCH * 2 * HWN * 4;       // reduced rowsums
    char* region = w;  // transpose buffers live here early; P~ overlays later
    u16* Tt = (u16*)region;
    u16* St = (u16*)(region + SZ_ACT);

    const size_t base_used = (size_t)(region - (char*)d_ws);
    int Bc = 8;
    while (Bc > 1) {
        size_t need = (size_t)NUMH * Bc * 2 * HWN * HWN * 2;  // P~ bf16
        size_t tneed = need > 2 * SZ_ACT ? need : 2 * SZ_ACT;
        if (base_used + tneed <= ws_size) break;
        Bc >>= 1;
    }
    u16* P = (u16*)region;

    zero_means_kernel<<<1, 64, 0, stream>>>(means);
    convw_kernel<<<512, 256, 0, stream>>>(Wq, Wk, Wv, Wqh, Wkh, Wvh);
    tconv_kernel<<<dim3(16, 8, 32), 256, 0, stream>>>(ftgt, fsrc, Tt, St);
    proj_qk_kernel<<<dim3(4, 8, 32), 256, 0, stream>>>(Tt, St, Wqh, Wkh, bq, bk, Qp, Kp);
    proj_v_kernel<<<dim3(8, 4, 16), 256, 0, stream>>>(Wvh, Tt, bv, Vb);

    const int nch = BATCH / Bc;
    for (int ch = 0; ch < nch; ch++) {
        const int b0 = ch * Bc;
        const int nls = NUMH * Bc * 2 * HWN;
        gemmE_kernel<<<dim3(8, 8, NUMH * Bc * 2), 256, 0, stream>>>(Qp, Kp, P, rs, means, b0, Bc);
        reduce_rs_kernel<<<(nls + 255) / 256, 256, 0, stream>>>(rs, ls, nls);
        gemmOut_kernel<<<dim3(8, 4, NUMH * Bc), 256, 0, stream>>>(Vb, P, ls, outp, b0, Bc);
    }
    alphas_kernel<<<1, 1, 0, stream>>>(means, outp + (out_size - 4));
}